// Round 1
// baseline (46.266 us; speedup 1.0000x reference)
//
#include <hip/hip_runtime.h>

#define NPOSE 262144
#define BLOCK 256
#define NBLK  (NPOSE / BLOCK)   // 1024

// FK translation for one chain of 4 matrices (36 consecutive floats,
// each matrix 3x3 row-major). translation = t0 + R0*(t1 + R1*(t2 + R2*t3))
// with R = [cross(c0,c1) | c0 | c1] (columns), t = c2.
__device__ __forceinline__ void chain_translation(const float* __restrict__ p, float out[3]) {
    float v0 = p[27 + 2], v1 = p[27 + 5], v2 = p[27 + 8];  // t3
#pragma unroll
    for (int j = 2; j >= 0; --j) {
        const float* m = p + j * 9;
        const float c00 = m[0], c01 = m[3], c02 = m[6];   // col0
        const float c10 = m[1], c11 = m[4], c12 = m[7];   // col1
        const float t0  = m[2], t1  = m[5], t2  = m[8];   // col2 = translation
        // cross(c0, c1)
        const float x0 = c01 * c12 - c02 * c11;
        const float x1 = c02 * c10 - c00 * c12;
        const float x2 = c00 * c11 - c01 * c10;
        const float w0 = t0 + x0 * v0 + c00 * v1 + c10 * v2;
        const float w1 = t1 + x1 * v0 + c01 * v1 + c11 * v2;
        const float w2 = t2 + x2 * v0 + c02 * v1 + c12 * v2;
        v0 = w0; v1 = w1; v2 = w2;
    }
    out[0] = v0; out[1] = v1; out[2] = v2;
}

__global__ __launch_bounds__(BLOCK) void fk_loss_kernel(const float* __restrict__ outp,
                                                        const float* __restrict__ gtp,
                                                        float* __restrict__ partials) {
    const int b = blockIdx.x * BLOCK + threadIdx.x;
    const float* po = outp + (size_t)b * 72;
    const float* pg = gtp  + (size_t)b * 72;

    float acc = 0.0f;
#pragma unroll
    for (int c = 0; c < 2; ++c) {
        float a[36], g[36];
        const float4* va = reinterpret_cast<const float4*>(po + c * 36);
        const float4* vg = reinterpret_cast<const float4*>(pg + c * 36);
#pragma unroll
        for (int k = 0; k < 9; ++k) {
            float4 x = va[k];
            a[4 * k + 0] = x.x; a[4 * k + 1] = x.y; a[4 * k + 2] = x.z; a[4 * k + 3] = x.w;
            float4 y = vg[k];
            g[4 * k + 0] = y.x; g[4 * k + 1] = y.y; g[4 * k + 2] = y.z; g[4 * k + 3] = y.w;
        }
        float ta[3], tg[3];
        chain_translation(a, ta);
        chain_translation(g, tg);
#pragma unroll
        for (int r = 0; r < 3; ++r) {
            const float d = ta[r] - tg[r];
            acc += d * d;
        }
    }

    // wave reduction (64 lanes)
#pragma unroll
    for (int off = 32; off > 0; off >>= 1)
        acc += __shfl_down(acc, off, 64);

    __shared__ float smem[BLOCK / 64];
    const int lane = threadIdx.x & 63;
    const int wid  = threadIdx.x >> 6;
    if (lane == 0) smem[wid] = acc;
    __syncthreads();
    if (threadIdx.x == 0) {
        float s = 0.0f;
#pragma unroll
        for (int w = 0; w < BLOCK / 64; ++w) s += smem[w];
        partials[blockIdx.x] = s;
    }
}

__global__ __launch_bounds__(256) void reduce_kernel(const float* __restrict__ partials,
                                                     float* __restrict__ out) {
    float s = 0.0f;
    for (int i = threadIdx.x; i < NBLK; i += 256) s += partials[i];
#pragma unroll
    for (int off = 32; off > 0; off >>= 1)
        s += __shfl_down(s, off, 64);
    __shared__ float smem[4];
    const int lane = threadIdx.x & 63;
    const int wid  = threadIdx.x >> 6;
    if (lane == 0) smem[wid] = s;
    __syncthreads();
    if (threadIdx.x == 0) {
        float t = smem[0] + smem[1] + smem[2] + smem[3];
        const float mean = t / (262144.0f * 6.0f);
        out[0] = mean;  // pos_loss
        out[1] = mean;  // vel_loss == pos_loss (gt_prev cancels algebraically)
    }
}

extern "C" void kernel_launch(void* const* d_in, const int* in_sizes, int n_in,
                              void* d_out, int out_size, void* d_ws, size_t ws_size,
                              hipStream_t stream) {
    const float* output_pose = (const float*)d_in[0];
    const float* gt_pose     = (const float*)d_in[1];
    // d_in[2] (gt_prev_pose) cancels algebraically: vel_loss == pos_loss.
    float* out = (float*)d_out;
    float* partials = (float*)d_ws;

    fk_loss_kernel<<<NBLK, BLOCK, 0, stream>>>(output_pose, gt_pose, partials);
    reduce_kernel<<<1, 256, 0, stream>>>(partials, out);
}

// Round 2
// 30.092 us; speedup vs baseline: 1.5375x; 1.5375x over previous
//
#include <hip/hip_runtime.h>

#define NPOSE 262144
#define BLOCK 128              // 1 pose per thread
#define PPB   128              // poses per block
#define NBLK  (NPOSE / PPB)    // 2048
#define PAD   73               // LDS row stride in floats: bank stride 9, gcd(9,32)=1 -> 2-way = free

// FK translation for one chain of 4 matrices (36 consecutive floats,
// each matrix 3x3 row-major). translation = t0 + R0*(t1 + R1*(t2 + R2*t3))
// with R = [cross(c0,c1) | c0 | c1] (columns), t = c2.
__device__ __forceinline__ void chain_translation(const float* __restrict__ p, float out[3]) {
    float v0 = p[27 + 2], v1 = p[27 + 5], v2 = p[27 + 8];  // t3
#pragma unroll
    for (int j = 2; j >= 0; --j) {
        const float* m = p + j * 9;
        const float c00 = m[0], c01 = m[3], c02 = m[6];   // col0
        const float c10 = m[1], c11 = m[4], c12 = m[7];   // col1
        const float t0  = m[2], t1  = m[5], t2  = m[8];   // col2 = translation
        const float x0 = c01 * c12 - c02 * c11;
        const float x1 = c02 * c10 - c00 * c12;
        const float x2 = c00 * c11 - c01 * c10;
        const float w0 = t0 + x0 * v0 + c00 * v1 + c10 * v2;
        const float w1 = t1 + x1 * v0 + c01 * v1 + c11 * v2;
        const float w2 = t2 + x2 * v0 + c02 * v1 + c12 * v2;
        v0 = w0; v1 = w1; v2 = w2;
    }
    out[0] = v0; out[1] = v1; out[2] = v2;
}

// Stage this block's 128-pose region (128*72 floats = 2304 float4, contiguous)
// into LDS with rows padded to PAD floats. Loads first (18 outstanding/thread),
// then LDS writes.
__device__ __forceinline__ void stage_block(const float* __restrict__ gsrc,
                                            float* __restrict__ lds, int tid) {
    const float4* __restrict__ g = reinterpret_cast<const float4*>(gsrc);
    float4 v[18];
#pragma unroll
    for (int i = 0; i < 18; ++i)
        v[i] = g[tid + i * BLOCK];          // perfectly coalesced: consecutive lanes, consecutive 16B
#pragma unroll
    for (int i = 0; i < 18; ++i) {
        const int f = tid + i * BLOCK;      // float4 index in block region
        const int p = f / 18;               // pose within block
        const int j = f % 18;               // float4 within pose
        float* d = &lds[p * PAD + 4 * j];
        d[0] = v[i].x; d[1] = v[i].y; d[2] = v[i].z; d[3] = v[i].w;
    }
}

__global__ __launch_bounds__(BLOCK) void fk_loss_kernel(const float* __restrict__ outp,
                                                        const float* __restrict__ gtp,
                                                        float* __restrict__ partials) {
    __shared__ float lds[PPB * PAD];        // 37376 B
    const int tid = threadIdx.x;
    const size_t base = (size_t)blockIdx.x * PPB * 72;

    // --- input A (output_pose): stage, FK both chains ---
    stage_block(outp + base, lds, tid);
    __syncthreads();
    float ta[2][3];
    {
        const float* row = &lds[tid * PAD];
        chain_translation(row, ta[0]);
        chain_translation(row + 36, ta[1]);
    }
    __syncthreads();

    // --- input B (gt_pose): stage, FK, diff ---
    stage_block(gtp + base, lds, tid);
    __syncthreads();
    float acc = 0.0f;
    {
        const float* row = &lds[tid * PAD];
        float tg[3];
        chain_translation(row, tg);
#pragma unroll
        for (int r = 0; r < 3; ++r) { const float d = ta[0][r] - tg[r]; acc += d * d; }
        chain_translation(row + 36, tg);
#pragma unroll
        for (int r = 0; r < 3; ++r) { const float d = ta[1][r] - tg[r]; acc += d * d; }
    }

    // wave reduction (64 lanes), then cross-wave via small smem
#pragma unroll
    for (int off = 32; off > 0; off >>= 1)
        acc += __shfl_down(acc, off, 64);

    __shared__ float smem[BLOCK / 64];
    const int lane = tid & 63;
    const int wid  = tid >> 6;
    if (lane == 0) smem[wid] = acc;
    __syncthreads();
    if (tid == 0) {
        float s = 0.0f;
#pragma unroll
        for (int w = 0; w < BLOCK / 64; ++w) s += smem[w];
        partials[blockIdx.x] = s;
    }
}

__global__ __launch_bounds__(256) void reduce_kernel(const float* __restrict__ partials,
                                                     float* __restrict__ out) {
    float s = 0.0f;
    for (int i = threadIdx.x; i < NBLK; i += 256) s += partials[i];
#pragma unroll
    for (int off = 32; off > 0; off >>= 1)
        s += __shfl_down(s, off, 64);
    __shared__ float smem[4];
    const int lane = threadIdx.x & 63;
    const int wid  = threadIdx.x >> 6;
    if (lane == 0) smem[wid] = s;
    __syncthreads();
    if (threadIdx.x == 0) {
        float t = smem[0] + smem[1] + smem[2] + smem[3];
        const float mean = t / (262144.0f * 6.0f);
        out[0] = mean;  // pos_loss
        out[1] = mean;  // vel_loss == pos_loss (gt_prev cancels algebraically)
    }
}

extern "C" void kernel_launch(void* const* d_in, const int* in_sizes, int n_in,
                              void* d_out, int out_size, void* d_ws, size_t ws_size,
                              hipStream_t stream) {
    const float* output_pose = (const float*)d_in[0];
    const float* gt_pose     = (const float*)d_in[1];
    // d_in[2] (gt_prev_pose) cancels algebraically: vel_loss == pos_loss.
    float* out = (float*)d_out;
    float* partials = (float*)d_ws;

    fk_loss_kernel<<<NBLK, BLOCK, 0, stream>>>(output_pose, gt_pose, partials);
    reduce_kernel<<<1, 256, 0, stream>>>(partials, out);
}

// Round 3
// 28.968 us; speedup vs baseline: 1.5972x; 1.0388x over previous
//
#include <hip/hip_runtime.h>

#define NPOSE  262144
#define NCHAIN (NPOSE * 2)     // two independent FK chains per pose
#define BLOCK  64              // single-wave blocks: barriers are wave-local
#define CPB    64              // chains per block
#define NBLK   (NCHAIN / CPB)  // 8192
#define PAD    37              // LDS row stride: bank stride 5, gcd(5,32)=1 -> 2-way = free

// FK translation for one chain of 4 matrices (36 consecutive floats, each 3x3
// row-major). translation = t0 + R0*(t1 + R1*(t2 + R2*t3)), R = [cross(c0,c1)|c0|c1].
__device__ __forceinline__ void chain_translation(const float* __restrict__ p, float out[3]) {
    float v0 = p[27 + 2], v1 = p[27 + 5], v2 = p[27 + 8];  // t3
#pragma unroll
    for (int j = 2; j >= 0; --j) {
        const float* m = p + j * 9;
        const float c00 = m[0], c01 = m[3], c02 = m[6];   // col0
        const float c10 = m[1], c11 = m[4], c12 = m[7];   // col1
        const float t0  = m[2], t1  = m[5], t2  = m[8];   // col2 = translation
        const float x0 = c01 * c12 - c02 * c11;
        const float x1 = c02 * c10 - c00 * c12;
        const float x2 = c00 * c11 - c01 * c10;
        const float w0 = t0 + x0 * v0 + c00 * v1 + c10 * v2;
        const float w1 = t1 + x1 * v0 + c01 * v1 + c11 * v2;
        const float w2 = t2 + x2 * v0 + c02 * v1 + c12 * v2;
        v0 = w0; v1 = w1; v2 = w2;
    }
    out[0] = v0; out[1] = v1; out[2] = v2;
}

__device__ __forceinline__ void write_rows(float* __restrict__ lds, const float4* v, int t) {
#pragma unroll
    for (int i = 0; i < 9; ++i) {
        const int f = t + 64 * i;        // float4 index in block region
        const int c = f / 9;             // chain within block
        const int j = f - 9 * c;         // float4 within chain
        float* d = &lds[c * PAD + 4 * j];
        d[0] = v[i].x; d[1] = v[i].y; d[2] = v[i].z; d[3] = v[i].w;
    }
}

__global__ __launch_bounds__(BLOCK, 4) void fk_loss_kernel(const float* __restrict__ outp,
                                                           const float* __restrict__ gtp,
                                                           float* __restrict__ partials) {
    __shared__ float lds[CPB * PAD];     // 9472 B -> 16 blocks/CU
    const int t = threadIdx.x;
    const size_t base4 = (size_t)blockIdx.x * (CPB * 9);   // float4 offset of block region
    const float4* __restrict__ ga = reinterpret_cast<const float4*>(outp) + base4;
    const float4* __restrict__ gb = reinterpret_cast<const float4*>(gtp) + base4;

    // Issue ALL 18 global loads up-front (perfectly coalesced), keep in VGPRs.
    float4 va[9], vb[9];
#pragma unroll
    for (int i = 0; i < 9; ++i) va[i] = ga[t + 64 * i];
#pragma unroll
    for (int i = 0; i < 9; ++i) vb[i] = gb[t + 64 * i];
    __builtin_amdgcn_sched_barrier(0);   // don't let the compiler sink the B loads

    // stage A, FK A
    write_rows(lds, va, t);
    __syncthreads();
    float ta[3];
    chain_translation(&lds[t * PAD], ta);
    __syncthreads();

    // stage B, FK B, diff
    write_rows(lds, vb, t);
    __syncthreads();
    float tg[3];
    chain_translation(&lds[t * PAD], tg);

    float acc = 0.0f;
#pragma unroll
    for (int r = 0; r < 3; ++r) { const float d = ta[r] - tg[r]; acc += d * d; }

    // single-wave reduction
#pragma unroll
    for (int off = 32; off > 0; off >>= 1)
        acc += __shfl_down(acc, off, 64);
    if (t == 0) partials[blockIdx.x] = acc;
}

__global__ __launch_bounds__(512) void reduce_kernel(const float* __restrict__ partials,
                                                     float* __restrict__ out) {
    const int t = threadIdx.x;
    const float4* __restrict__ p4 = reinterpret_cast<const float4*>(partials); // 2048 float4
    float s = 0.0f;
#pragma unroll
    for (int i = 0; i < 4; ++i) {
        const float4 v = p4[t + 512 * i];
        s += v.x + v.y + v.z + v.w;
    }
#pragma unroll
    for (int off = 32; off > 0; off >>= 1)
        s += __shfl_down(s, off, 64);
    __shared__ float smem[8];
    const int lane = t & 63, wid = t >> 6;
    if (lane == 0) smem[wid] = s;
    __syncthreads();
    if (t == 0) {
        float tot = 0.0f;
#pragma unroll
        for (int w = 0; w < 8; ++w) tot += smem[w];
        const float mean = tot / (262144.0f * 6.0f);
        out[0] = mean;  // pos_loss
        out[1] = mean;  // vel_loss == pos_loss (gt_prev cancels algebraically)
    }
}

extern "C" void kernel_launch(void* const* d_in, const int* in_sizes, int n_in,
                              void* d_out, int out_size, void* d_ws, size_t ws_size,
                              hipStream_t stream) {
    const float* output_pose = (const float*)d_in[0];
    const float* gt_pose     = (const float*)d_in[1];
    // d_in[2] (gt_prev_pose) cancels algebraically: vel_loss == pos_loss.
    float* out = (float*)d_out;
    float* partials = (float*)d_ws;   // 8192 floats = 32 KB

    fk_loss_kernel<<<NBLK, BLOCK, 0, stream>>>(output_pose, gt_pose, partials);
    reduce_kernel<<<1, 512, 0, stream>>>(partials, out);
}